// Round 2
// baseline (230.895 us; speedup 1.0000x reference)
//
#include <hip/hip_runtime.h>

// Depth-3 Haar wavelet packet transform along last dim (S=8192), rows = B*C = 4096.
// out[row, n*1024 + j] = c^3 * sum_t (-1)^(b1*t0 + b2*t1 + b3*t2) x[row, 8j+t],
// n = 4*b1 + 2*b2 + b3, c^3 = 2^{-1.5}.
//
// One thread per 32 consecutive inputs (= exactly one 128B cache line):
//   - 8 x global_load_dwordx4 at 128B lane stride: a wave's 8 loads revisit the
//     same 64 lines back-to-back -> 1 DRAM fetch per line, rest L1 hits.
//   - 4 independent 8-point transforms fully in-register (no LDS, no shfl,
//     no barrier).
//   - per node, the thread owns 4 consecutive j -> ONE float4 store per node,
//     consecutive lanes -> perfect 1KiB/wave store instructions.
// Per 128B in + 128B out: 8 loads + 8 stores + ~128 VALU. Pure stream.

#define C3 0.35355339059327373f

__global__ __launch_bounds__(256) void swpt3_kernel(const float4* __restrict__ x,
                                                    float* __restrict__ out) {
    const unsigned g   = blockIdx.x * 256u + threadIdx.x;  // one thread per 32 floats
    const unsigned row = g >> 8;                           // 8192/32 = 256 threads per row
    const unsigned c   = g & 255u;                         // 128B-chunk index within row

    const float4* xp = x + (size_t)row * 2048u + (size_t)c * 8u;

    const float4 v0 = xp[0];
    const float4 v1 = xp[1];
    const float4 v2 = xp[2];
    const float4 v3 = xp[3];
    const float4 v4 = xp[4];
    const float4 v5 = xp[5];
    const float4 v6 = xp[6];
    const float4 v7 = xp[7];

    float4 R0, R1, R2, R3, R4, R5, R6, R7;   // R<n>.q = node n output for subgroup q

#define DO8(va, vb, COMP) do {                                  \
        const float s0 = va.x + va.y, d0 = va.x - va.y;         \
        const float s1 = va.z + va.w, d1 = va.z - va.w;         \
        const float s2 = vb.x + vb.y, d2 = vb.x - vb.y;         \
        const float s3 = vb.z + vb.w, d3 = vb.z - vb.w;         \
        const float ss0 = s0 + s1, sd0 = s0 - s1;               \
        const float ss1 = s2 + s3, sd1 = s2 - s3;               \
        const float ds0 = d0 + d1, dd0 = d0 - d1;               \
        const float ds1 = d2 + d3, dd1 = d2 - d3;               \
        R0.COMP = (ss0 + ss1) * C3;                             \
        R1.COMP = (ss0 - ss1) * C3;                             \
        R2.COMP = (sd0 + sd1) * C3;                             \
        R3.COMP = (sd0 - sd1) * C3;                             \
        R4.COMP = (ds0 + ds1) * C3;                             \
        R5.COMP = (ds0 - ds1) * C3;                             \
        R6.COMP = (dd0 + dd1) * C3;                             \
        R7.COMP = (dd0 - dd1) * C3;                             \
    } while (0)

    DO8(v0, v1, x);
    DO8(v2, v3, y);
    DO8(v4, v5, z);
    DO8(v6, v7, w);
#undef DO8

    float* orow = out + (size_t)row * 8192u;
    ((float4*)(orow        ))[c] = R0;
    ((float4*)(orow + 1024u))[c] = R1;
    ((float4*)(orow + 2048u))[c] = R2;
    ((float4*)(orow + 3072u))[c] = R3;
    ((float4*)(orow + 4096u))[c] = R4;
    ((float4*)(orow + 5120u))[c] = R5;
    ((float4*)(orow + 6144u))[c] = R6;
    ((float4*)(orow + 7168u))[c] = R7;
}

extern "C" void kernel_launch(void* const* d_in, const int* in_sizes, int n_in,
                              void* d_out, int out_size, void* d_ws, size_t ws_size,
                              hipStream_t stream) {
    const float4* x = (const float4*)d_in[0];
    float* out = (float*)d_out;
    // 64*64*8192 floats / 32 per thread = 1,048,576 threads = 4096 blocks x 256.
    swpt3_kernel<<<4096, 256, 0, stream>>>(x, out);
}

// Round 3
// 227.045 us; speedup vs baseline: 1.0170x; 1.0170x over previous
//
#include <hip/hip_runtime.h>

// Depth-3 Haar wavelet packet transform along last dim (S=8192), rows = B*C = 4096.
// out[row, n*1024 + j] = c^3 * sum_t (-1)^(b1*t0 + b2*t1 + b3*t2) x[row, 8j+t],
// n = 4*b1 + 2*b2 + b3, c^3 = 2^{-1.5}.
//
// One block per row. LDS is used purely as the transpose medium:
//   stage 1: 8 coalesced float4 loads per thread (8 outstanding VMEM/wave = deep
//            MLP), written to LDS with XOR swizzle  a ^= ((a>>7)&7)<<4
//            (permutes 16B slots within each 128B chunk; write stays
//            conflict-free, read becomes conflict-free).
//   stage 2: 8 swizzled ds_read_b128 -> thread owns 32 consecutive inputs ->
//            4 independent 8-point transforms in-register (no shuffles) ->
//            8 coalesced float4 stores (1 KiB contiguous per wave per node).
// One barrier per 8192 floats. DS ops per output float: 0.5 (R0 had 2.25).

#define C3 0.35355339059327373f

__device__ __forceinline__ unsigned swz(unsigned a) {
    return a ^ (((a >> 7) & 7u) << 4);
}

__global__ __launch_bounds__(256) void swpt3_kernel(const float4* __restrict__ x,
                                                    float* __restrict__ out) {
    __shared__ float lds[8192];          // 32 KiB = one full row
    char* ldsb = (char*)lds;

    const unsigned t   = threadIdx.x;
    const unsigned row = blockIdx.x;

    const float4* xr = x + (size_t)row * 2048u;

    // stage 1: coalesced global loads -> swizzled LDS writes
    #pragma unroll
    for (unsigned k = 0; k < 8; ++k) {
        const float4 v = xr[t + 256u * k];
        *(float4*)(ldsb + swz((t + 256u * k) * 16u)) = v;
    }

    __syncthreads();

    // stage 2: swizzled ds_read_b128 -> 32 consecutive floats per thread
    float4 v0 = *(const float4*)(ldsb + swz(t * 128u + 0u));
    float4 v1 = *(const float4*)(ldsb + swz(t * 128u + 16u));
    float4 v2 = *(const float4*)(ldsb + swz(t * 128u + 32u));
    float4 v3 = *(const float4*)(ldsb + swz(t * 128u + 48u));
    float4 v4 = *(const float4*)(ldsb + swz(t * 128u + 64u));
    float4 v5 = *(const float4*)(ldsb + swz(t * 128u + 80u));
    float4 v6 = *(const float4*)(ldsb + swz(t * 128u + 96u));
    float4 v7 = *(const float4*)(ldsb + swz(t * 128u + 112u));

    float4 R0, R1, R2, R3, R4, R5, R6, R7;   // R<n>.q = node n, j = 4t+q

#define DO8(va, vb, COMP) do {                                  \
        const float s0 = va.x + va.y, d0 = va.x - va.y;         \
        const float s1 = va.z + va.w, d1 = va.z - va.w;         \
        const float s2 = vb.x + vb.y, d2 = vb.x - vb.y;         \
        const float s3 = vb.z + vb.w, d3 = vb.z - vb.w;         \
        const float ss0 = s0 + s1, sd0 = s0 - s1;               \
        const float ss1 = s2 + s3, sd1 = s2 - s3;               \
        const float ds0 = d0 + d1, dd0 = d0 - d1;               \
        const float ds1 = d2 + d3, dd1 = d2 - d3;               \
        R0.COMP = (ss0 + ss1) * C3;                             \
        R1.COMP = (ss0 - ss1) * C3;                             \
        R2.COMP = (sd0 + sd1) * C3;                             \
        R3.COMP = (sd0 - sd1) * C3;                             \
        R4.COMP = (ds0 + ds1) * C3;                             \
        R5.COMP = (ds0 - ds1) * C3;                             \
        R6.COMP = (dd0 + dd1) * C3;                             \
        R7.COMP = (dd0 - dd1) * C3;                             \
    } while (0)

    DO8(v0, v1, x);
    DO8(v2, v3, y);
    DO8(v4, v5, z);
    DO8(v6, v7, w);
#undef DO8

    // stage 3: per node one coalesced float4 store (j = 4t .. 4t+3)
    float* orow = out + (size_t)row * 8192u;
    ((float4*)(orow        ))[t] = R0;
    ((float4*)(orow + 1024u))[t] = R1;
    ((float4*)(orow + 2048u))[t] = R2;
    ((float4*)(orow + 3072u))[t] = R3;
    ((float4*)(orow + 4096u))[t] = R4;
    ((float4*)(orow + 5120u))[t] = R5;
    ((float4*)(orow + 6144u))[t] = R6;
    ((float4*)(orow + 7168u))[t] = R7;
}

extern "C" void kernel_launch(void* const* d_in, const int* in_sizes, int n_in,
                              void* d_out, int out_size, void* d_ws, size_t ws_size,
                              hipStream_t stream) {
    const float4* x = (const float4*)d_in[0];
    float* out = (float*)d_out;
    // one block per row: 64*64 = 4096 blocks x 256 threads
    swpt3_kernel<<<4096, 256, 0, stream>>>(x, out);
}